// Round 3
// baseline (2116.506 us; speedup 1.0000x reference)
//
#include <hip/hip_runtime.h>
#include <hip/hip_bf16.h>
#include <stdint.h>

typedef short s8v __attribute__((ext_vector_type(8)));
typedef float f4v __attribute__((ext_vector_type(4)));

// ---------------- W pack: [co][ci][kh][kw] fp32 -> [kh*5+kw][co][ci] bf16 ----------------
__global__ void wpack_kernel(const float* __restrict__ W, __hip_bfloat16* __restrict__ Wr) {
  int i = blockIdx.x * 256 + threadIdx.x;  // < 819200
  int ci = i & 255;
  int rest = i >> 8;
  int co = rest & 127;
  int pos = rest >> 7;  // kh*5+kw
  Wr[i] = __float2bfloat16(W[(co * 256 + ci) * 25 + pos]);
}

// ---------------- Upsample: x NCHW fp32 (8,256,64,64) -> up NHWC bf16 (8,128,128,256) ----------------
__global__ __launch_bounds__(256, 2) void upsample_kernel(const float* __restrict__ x,
                                                          __hip_bfloat16* __restrict__ up) {
  __shared__ __hip_bfloat16 lx[10 * 48 * 66];  // [ih 10][iw 48][c 64 + 2 pad]
  const int tid = threadIdx.x;
  const int bx = blockIdx.x;
  const int owb = bx & 1;
  const int ohb = (bx >> 1) & 7;
  const int cb = (bx >> 4) & 3;
  const int b = bx >> 6;
  const int oh0 = ohb * 16, ow0 = owb * 64, c0 = cb * 64;
  const int ih0 = (oh0 >> 1) - 1;
  const int iw_lo = (ow0 >> 1) - 1;
  const int aligned = (iw_lo < 0 ? 0 : iw_lo) & ~15;

#pragma unroll 1
  for (int i = tid; i < 64 * 10 * 12; i += 256) {
    int c = i / 120;
    int rem = i - c * 120;
    int r = rem / 12;
    int w4 = (rem - r * 12) * 4;
    int gr = ih0 + r;
    gr = gr < 0 ? 0 : (gr > 63 ? 63 : gr);
    const float4 v = *(const float4*)&x[(((b * 256 + c0 + c) * 64) + gr) * 64 + aligned + w4];
    int base = (r * 48 + w4) * 66 + c;
    lx[base]       = __float2bfloat16(v.x);
    lx[base + 66]  = __float2bfloat16(v.y);
    lx[base + 132] = __float2bfloat16(v.z);
    lx[base + 198] = __float2bfloat16(v.w);
  }
  __syncthreads();

  const int c_l = tid & 63;
  const int owq = tid >> 6;
#pragma unroll 1
  for (int it = 0; it < 256; ++it) {
    int oh_l = it >> 4;
    int ow_l = (it & 15) * 4 + owq;
    int oh = oh0 + oh_l, ow = ow0 + ow_l;
    int ihA = (oh >> 1) - ((oh & 1) ^ 1);
    float wh = (oh & 1) ? 0.75f : 0.25f;
    int iwA = (ow >> 1) - ((ow & 1) ^ 1);
    float wwt = (ow & 1) ? 0.75f : 0.25f;
    int r0 = ihA - ih0;
    int w0 = (iwA < 0 ? 0 : iwA) - aligned;
    int w1t = iwA + 1; w1t = w1t > 63 ? 63 : w1t;
    int w1 = w1t - aligned;
    float t00 = __bfloat162float(lx[(r0 * 48 + w0) * 66 + c_l]);
    float t01 = __bfloat162float(lx[(r0 * 48 + w1) * 66 + c_l]);
    float t10 = __bfloat162float(lx[((r0 + 1) * 48 + w0) * 66 + c_l]);
    float t11 = __bfloat162float(lx[((r0 + 1) * 48 + w1) * 66 + c_l]);
    float v = wh * (wwt * t00 + (1.f - wwt) * t01) + (1.f - wh) * (wwt * t10 + (1.f - wwt) * t11);
    up[(((size_t)(b * 128 + oh) * 128) + ow) * 256 + c0 + c_l] = __float2bfloat16(v);
  }
}

// ---------------- Conv v3: M=512 (4 oh rows) x N=128, register-path staging, no LDS-DMA ----------------
// grid: 256 blocks = b(8) x ohq(32), 512 threads (8 waves: wave = oh_l(4) x ow-half(2))
// Rounds R=0..199: kh=R/40, cb=(R/5)&7 (32ch), kw=R%5. K=32 per round, 32 MFMA/wave/round.
__global__ __launch_bounds__(512, 2) void conv_kernel(const __hip_bfloat16* __restrict__ up,
                                                      const __hip_bfloat16* __restrict__ Wr,
                                                      float* __restrict__ out,
                                                      float* __restrict__ pstats) {
  // lA: chunk16 = kq*530 + irl*132 + iw  (4 kq x [4 irl x 132 iw + 2 pad]) = 2120 chunks = 33920 B
  // lB: 2 bufs x 512 chunks (kq*128 + (n ^ (kq<<2)))                       = 16384 B
  // lsum/lssq: 256 floats; ep (epilogue, [16][516] fp32 = 33024 B) aliases lA.
  __shared__ __align__(16) char smem[33920 + 16384 + 1024];
  unsigned short* lA = (unsigned short*)smem;
  unsigned short* lB = (unsigned short*)(smem + 33920);
  float* ep = (float*)smem;
  float* lsum = (float*)(smem + 33920 + 16384);
  float* lssq = lsum + 128;

  const int tid = threadIdx.x;
  const int lane = tid & 63;
  const int wave = tid >> 6;            // 0..7
  const int b = blockIdx.x >> 5;
  const int oh0 = (blockIdx.x & 31) * 4;
  const int lane15 = lane & 15;
  const int quad = lane >> 4;
  const int oh_l = wave >> 1;           // wave's output row 0..3
  const int ow_base = (wave & 1) * 64;  // wave's ow slice

  if (tid < 256) lsum[tid] = 0.f;       // lsum+lssq contiguous
  if (tid < 64) {                       // zero halo cols iw in {0,1,130,131} for all kq,irl
    int kq = tid & 3, irl = (tid >> 2) & 3, h = tid >> 4;
    int iw = (h < 2) ? h : (128 + h);
    f4v z = {0.f, 0.f, 0.f, 0.f};
    *(f4v*)&lA[(kq * 530 + irl * 132 + iw) * 8] = z;
  }

  f4v acc[4][8];
#pragma unroll
  for (int i = 0; i < 4; ++i)
#pragma unroll
    for (int j = 0; j < 8; ++j) acc[i][j] = (f4v){0.f, 0.f, 0.f, 0.f};

  // Per-thread weight staging geometry: thread covers (cout t_n, ch-chunk t_kq)
  const int t_kq = tid & 3;
  const int t_n = tid >> 2;  // 0..127
  const int wr_off = (t_kq * 128 + (t_n ^ (t_kq << 2))) * 8;  // ushort idx within a buf

  // Prologue: lB[0] <- round 0 (pos=0,cb=0); prefetch round 1 (pos=1? no: R=1 -> kh0,cb0,kw1 -> pos=1)
  s8v pB = *(const s8v*)&Wr[(size_t)t_n * 256 + t_kq * 8];  // round 0: pos 0, cb 0
  *(s8v*)&lB[wr_off] = pB;  // buf 0
  pB = *(const s8v*)&Wr[(size_t)32768 + t_n * 256 + t_kq * 8];  // round 1: pos 1, cb 0

#pragma unroll 1
  for (int R = 0; R < 200; ++R) {
    const int kw = R % 5;
    __syncthreads();  // lB[R&1] (written last round) + prior-round lA reads drained

    if (kw == 0) {  // stage lA for group (kh = R/40, cb = (R/5)&7)
      const int kh = R / 40;
      const int cb = (R / 5) & 7;
      s8v ra[4];
#pragma unroll
      for (int it = 0; it < 4; ++it) {
        int idx = it * 512 + tid;        // 0..2047
        int kq = idx & 3;
        int iw = (idx >> 2) & 127;
        int irl = idx >> 9;
        int ihg = oh0 + kh - 2 + irl;
        if (ihg >= 0 && ihg < 128)
          ra[it] = *(const s8v*)&up[((size_t)(b * 128 + ihg) * 128 + iw) * 256 + cb * 32 + kq * 8];
        else
          ra[it] = (s8v){0, 0, 0, 0, 0, 0, 0, 0};
      }
#pragma unroll
      for (int it = 0; it < 4; ++it) {
        int idx = it * 512 + tid;
        int kq = idx & 3;
        int iw = (idx >> 2) & 127;
        int irl = idx >> 9;
        *(s8v*)&lA[(kq * 530 + irl * 132 + iw + 2) * 8] = ra[it];
      }
    }

    // write NEXT round's lB (prefetched) into the other buffer
    *(s8v*)&lB[((R + 1) & 1) * 4096 + wr_off] = pB;

    if (kw == 0) __syncthreads();  // make freshly staged lA visible before reads

    // prefetch round R+2's weights (outstanding across the MFMA section)
    {
      int idx2 = (R + 2 < 200) ? (R + 2) : 0;
      int pos2 = (idx2 / 40) * 5 + idx2 % 5;
      int cb2 = (idx2 / 5) & 7;
      pB = *(const s8v*)&Wr[(size_t)pos2 * 32768 + cb2 * 32 + t_n * 256 + t_kq * 8];
    }

    // fragments + MFMA
    const unsigned short* lBc = lB + (R & 1) * 4096;
    s8v bfr[8];
#pragma unroll
    for (int nt = 0; nt < 8; ++nt) {
      int n = nt * 16 + lane15;
      bfr[nt] = *(const s8v*)&lBc[(quad * 128 + (n ^ (quad << 2))) * 8];
    }
    s8v afr[4];
#pragma unroll
    for (int mt = 0; mt < 4; ++mt) {
      int iw = ow_base + mt * 16 + lane15 + kw;  // halo coords 0..131
      afr[mt] = *(const s8v*)&lA[(quad * 530 + oh_l * 132 + iw) * 8];
    }
#pragma unroll
    for (int mt = 0; mt < 4; ++mt)
#pragma unroll
      for (int nt = 0; nt < 8; ++nt)
        acc[mt][nt] = __builtin_amdgcn_mfma_f32_16x16x32_bf16(afr[mt], bfr[nt], acc[mt][nt], 0, 0, 0);
  }

  __syncthreads();  // all LDS reads done; lA region now reusable as ep
#pragma unroll 1
  for (int g = 0; g < 8; ++g) {  // cout groups of 16 (g == nt)
#pragma unroll
    for (int mt = 0; mt < 4; ++mt) {
      // D layout: n = lane15, m(within 16) = quad*4 + reg
      int m = oh_l * 128 + ow_base + mt * 16 + quad * 4;
      *(f4v*)&ep[lane15 * 516 + m] = acc[mt][g];
    }
    __syncthreads();
#pragma unroll
    for (int it = 0; it < 4; ++it) {
      int idx = it * 512 + tid;     // 0..2047
      int nl = idx >> 7;            // 0..15
      int mi = (idx & 127) * 4;     // 0..508
      f4v v = *(const f4v*)&ep[nl * 516 + mi];
      int cout = g * 16 + nl;
      int ohh = oh0 + (mi >> 7);
      int oww = mi & 127;
      *(f4v*)&out[((size_t)(b * 128 + cout) * 128 + ohh) * 128 + oww] = v;
      float s = v.x + v.y + v.z + v.w;
      float ss = v.x * v.x + v.y * v.y + v.z * v.z + v.w * v.w;
#pragma unroll
      for (int off = 16; off > 0; off >>= 1) {
        s += __shfl_xor(s, off, 32);
        ss += __shfl_xor(ss, off, 32);
      }
      if ((lane & 31) == 0) {
        atomicAdd(&lsum[cout], s);
        atomicAdd(&lssq[cout], ss);
      }
    }
    __syncthreads();
  }
  if (tid < 128) {
    int bin = (blockIdx.x & 31) * 256;
    atomicAdd(&pstats[bin + tid], lsum[tid]);
    atomicAdd(&pstats[bin + 128 + tid], lssq[tid]);
  }
}

// ---------------- BN: reduce 32 bins + scale/bias ----------------
__global__ void scalebias_kernel(const float* __restrict__ pstats, const float* __restrict__ gamma,
                                 const float* __restrict__ beta, float* __restrict__ sb) {
  __shared__ float red[256];
  int t = threadIdx.x;
  float s = 0.f;
#pragma unroll
  for (int bin = 0; bin < 32; ++bin) s += pstats[bin * 256 + t];
  red[t] = s;
  __syncthreads();
  if (t < 128) {
    float mean = red[t] * (1.f / 131072.f);
    float var = red[128 + t] * (1.f / 131072.f) - mean * mean;
    float inv = gamma[t] * rsqrtf(var + 1e-5f);
    sb[t] = inv;
    sb[128 + t] = beta[t] - mean * inv;
  }
}

// ---------------- Normalize + ReLU in-place on d_out ----------------
__global__ void norm_kernel(float* __restrict__ out, const float* __restrict__ sb) {
  int i = blockIdx.x * 256 + threadIdx.x;  // float4 index
  f4v v = ((f4v*)out)[i];
  int c = (i >> 12) & 127;
  float sc = sb[c], bi = sb[128 + c];
  v.x = fmaxf(fmaf(v.x, sc, bi), 0.f);
  v.y = fmaxf(fmaf(v.y, sc, bi), 0.f);
  v.z = fmaxf(fmaf(v.z, sc, bi), 0.f);
  v.w = fmaxf(fmaf(v.w, sc, bi), 0.f);
  ((f4v*)out)[i] = v;
}

extern "C" void kernel_launch(void* const* d_in, const int* in_sizes, int n_in,
                              void* d_out, int out_size, void* d_ws, size_t ws_size,
                              hipStream_t stream) {
  (void)in_sizes; (void)n_in; (void)out_size; (void)ws_size;
  const float* x = (const float*)d_in[0];
  const float* W = (const float*)d_in[1];
  const float* gamma = (const float*)d_in[2];
  const float* beta = (const float*)d_in[3];
  float* out = (float*)d_out;
  char* ws = (char*)d_ws;
  __hip_bfloat16* up = (__hip_bfloat16*)ws;                       // 67,108,864 B
  __hip_bfloat16* Wr = (__hip_bfloat16*)(ws + 67108864);          // 1,638,400 B
  float* pstats = (float*)(ws + 67108864 + 1638400);              // 32 bins x 256 floats
  float* sb = pstats + 32 * 256;

  hipMemsetAsync(pstats, 0, 32 * 256 * sizeof(float), stream);
  wpack_kernel<<<3200, 256, 0, stream>>>(W, Wr);
  upsample_kernel<<<512, 256, 0, stream>>>(x, up);
  conv_kernel<<<256, 512, 0, stream>>>(up, Wr, out, pstats);
  scalebias_kernel<<<1, 256, 0, stream>>>(pstats, gamma, beta, sb);
  norm_kernel<<<16384, 256, 0, stream>>>(out, sb);
}

// Round 4
// 2087.604 us; speedup vs baseline: 1.0138x; 1.0138x over previous
//
#include <hip/hip_runtime.h>
#include <hip/hip_bf16.h>
#include <stdint.h>

typedef short s8v __attribute__((ext_vector_type(8)));
typedef float f4v __attribute__((ext_vector_type(4)));

// ---------------- W pack: [co][ci][kh][kw] fp32 -> [pos 25][cb 8][cout 128][c32] bf16 ----------------
__global__ void wpack_kernel(const float* __restrict__ W, __hip_bfloat16* __restrict__ Wr) {
  int i = blockIdx.x * 256 + threadIdx.x;  // < 819200
  int c32 = i & 31;
  int n = (i >> 5) & 127;
  int cb = (i >> 12) & 7;
  int pos = i >> 15;
  Wr[i] = __float2bfloat16(W[(n * 256 + cb * 32 + c32) * 25 + pos]);
}

// ---------------- Upsample: x NCHW fp32 -> up [b][h 128][cb 8][w 128][c32] bf16 ----------------
__global__ __launch_bounds__(256, 2) void upsample_kernel(const float* __restrict__ x,
                                                          __hip_bfloat16* __restrict__ up) {
  __shared__ __hip_bfloat16 lx[10 * 48 * 66];  // [ih 10][iw 48][c 64 + 2 pad]
  const int tid = threadIdx.x;
  const int bx = blockIdx.x;
  const int owb = bx & 1;
  const int ohb = (bx >> 1) & 7;
  const int cbb = (bx >> 4) & 3;
  const int b = bx >> 6;
  const int oh0 = ohb * 16, ow0 = owb * 64, c0 = cbb * 64;
  const int ih0 = (oh0 >> 1) - 1;
  const int iw_lo = (ow0 >> 1) - 1;
  const int aligned = (iw_lo < 0 ? 0 : iw_lo) & ~15;

#pragma unroll 1
  for (int i = tid; i < 64 * 10 * 12; i += 256) {
    int c = i / 120;
    int rem = i - c * 120;
    int r = rem / 12;
    int w4 = (rem - r * 12) * 4;
    int gr = ih0 + r;
    gr = gr < 0 ? 0 : (gr > 63 ? 63 : gr);
    const float4 v = *(const float4*)&x[(((b * 256 + c0 + c) * 64) + gr) * 64 + aligned + w4];
    int base = (r * 48 + w4) * 66 + c;
    lx[base]       = __float2bfloat16(v.x);
    lx[base + 66]  = __float2bfloat16(v.y);
    lx[base + 132] = __float2bfloat16(v.z);
    lx[base + 198] = __float2bfloat16(v.w);
  }
  __syncthreads();

  const int c_l = tid & 63;
  const int owq = tid >> 6;
  const int cb_hi = cbb * 2 + (c_l >> 5);  // global 32-ch slice
  const int c32 = c_l & 31;
#pragma unroll 1
  for (int it = 0; it < 256; ++it) {
    int oh_l = it >> 4;
    int ow_l = (it & 15) * 4 + owq;
    int oh = oh0 + oh_l, ow = ow0 + ow_l;
    int ihA = (oh >> 1) - ((oh & 1) ^ 1);
    float wh = (oh & 1) ? 0.75f : 0.25f;
    int iwA = (ow >> 1) - ((ow & 1) ^ 1);
    float wwt = (ow & 1) ? 0.75f : 0.25f;
    int r0 = ihA - ih0;
    int w0 = (iwA < 0 ? 0 : iwA) - aligned;
    int w1t = iwA + 1; w1t = w1t > 63 ? 63 : w1t;
    int w1 = w1t - aligned;
    float t00 = __bfloat162float(lx[(r0 * 48 + w0) * 66 + c_l]);
    float t01 = __bfloat162float(lx[(r0 * 48 + w1) * 66 + c_l]);
    float t10 = __bfloat162float(lx[((r0 + 1) * 48 + w0) * 66 + c_l]);
    float t11 = __bfloat162float(lx[((r0 + 1) * 48 + w1) * 66 + c_l]);
    float v = wh * (wwt * t00 + (1.f - wwt) * t01) + (1.f - wh) * (wwt * t10 + (1.f - wwt) * t11);
    up[((((size_t)(b * 128 + oh) * 8) + cb_hi) * 128 + ow) * 32 + c32] = __float2bfloat16(v);
  }
}

// ---------------- Conv v4: block = 2 oh rows x 128 cout; lA(6 rows x 32ch) reused by all 25 taps ----
// grid: 512 = b(8) x ohpair(64); 256 threads (4 waves: oh_l = w>>1, ow half = w&1)
// Round r = cb*25 + pos (cb 0..7 = 32ch slice, pos = kh*5+kw). 1 barrier/round; lB dbuf prefetch d=2.
__global__ __launch_bounds__(256, 2) void conv_kernel(const __hip_bfloat16* __restrict__ up,
                                                      const __hip_bfloat16* __restrict__ Wr,
                                                      float* __restrict__ out,
                                                      float* __restrict__ pstats) {
  // lA: chunk = q*794 + row*132 + iw  (4 q-planes x [6 rows x 132 iw + 2 pad]) = 50816 B
  // lB: 2 bufs x 520 chunks (q*130 + n)                                        = 16640 B
  // lsum/lssq 1024 B.  ep [16][260] fp32 (16640 B) aliases lA in epilogue.
  __shared__ __align__(16) char smem[50816 + 16640 + 1024];
  unsigned short* lA = (unsigned short*)smem;
  unsigned short* lB = (unsigned short*)(smem + 50816);
  float* ep = (float*)smem;
  float* lsum = (float*)(smem + 50816 + 16640);
  float* lssq = lsum + 128;

  const int tid = threadIdx.x;
  const int lane = tid & 63;
  const int wave = tid >> 6;
  const int b = blockIdx.x >> 6;
  const int oh0 = (blockIdx.x & 63) * 2;
  const int lane15 = lane & 15;
  const int quad = lane >> 4;
  const int oh_l = wave >> 1;
  const int owb = (wave & 1) * 64;
  const s8v zero8 = {0, 0, 0, 0, 0, 0, 0, 0};

  lsum[tid] = 0.f;  // 256 floats = lsum+lssq
  if (tid < 96) {   // zero halo cols iw in {0,1,130,131} for all q,row
    int q = tid & 3;
    int t24 = tid >> 2;          // 0..23
    int h = t24 / 6;             // 0..3
    int row = t24 - h * 6;       // 0..5
    int iw = (h < 2) ? h : (128 + h);
    *(s8v*)&lA[(q * 794 + row * 132 + iw) * 8] = zero8;
  }

  f4v acc[4][8];
#pragma unroll
  for (int i = 0; i < 4; ++i)
#pragma unroll
    for (int j = 0; j < 8; ++j) acc[i][j] = (f4v){0.f, 0.f, 0.f, 0.f};

  // weight staging: thread covers (q = tid&3, n in {wn, wn+64})
  const int wq = tid & 3;
  const int wn = tid >> 2;  // 0..63
  // prologue: lB buf0 <- round 0 (pos0,cb0); prefetch round 1 (pos1,cb0)
  s8v p0 = *(const s8v*)&Wr[(size_t)wn * 32 + wq * 8];
  s8v p1 = *(const s8v*)&Wr[(size_t)(wn + 64) * 32 + wq * 8];
  *(s8v*)&lB[(wq * 130 + wn) * 8] = p0;
  *(s8v*)&lB[(wq * 130 + wn + 64) * 8] = p1;
  p0 = *(const s8v*)&Wr[32768 + (size_t)wn * 32 + wq * 8];
  p1 = *(const s8v*)&Wr[32768 + (size_t)(wn + 64) * 32 + wq * 8];

#pragma unroll 1
  for (int r = 0; r < 200; ++r) {
    const int cb = r / 25;
    const int pos = r - cb * 25;
    const int kh = pos / 5;
    const int kw = pos - kh * 5;

    if (pos == 0) {  // stage lA for this 32-ch slice (all 6 rows)
      __syncthreads();  // prior rounds' lA reads complete
      s8v ra[12];
#pragma unroll
      for (int it = 0; it < 12; ++it) {
        int g = it * 256 + tid;  // 0..3071
        int row = g >> 9;
        int ihg = oh0 - 2 + row;
        int cr = g & 511;        // 16B chunk within the 8KB row-slice
        if (ihg >= 0 && ihg < 128)
          ra[it] = *(const s8v*)&up[((((size_t)(b * 128 + ihg) * 8) + cb) * 128 * 32) + cr * 8];
        else
          ra[it] = zero8;
      }
#pragma unroll
      for (int it = 0; it < 12; ++it) {
        int g = it * 256 + tid;
        int row = g >> 9;
        int w = (g >> 2) & 127;
        int q = g & 3;
        *(s8v*)&lA[(q * 794 + row * 132 + w + 2) * 8] = ra[it];
      }
    }

    __syncthreads();  // lA RAW + lB[r&1] RAW + lB[(r+1)&1] WAR (reads were last round)

    // write next round's weights into the other buffer
    {
      unsigned short* lBn = lB + ((r + 1) & 1) * 4160;
      *(s8v*)&lBn[(wq * 130 + wn) * 8] = p0;
      *(s8v*)&lBn[(wq * 130 + wn + 64) * 8] = p1;
    }
    // prefetch round r+2's weights (in flight across this round's MFMA)
    {
      int rr = (r + 2 < 200) ? (r + 2) : 0;
      int cb2 = rr / 25;
      int pos2 = rr - cb2 * 25;
      size_t base = (size_t)(pos2 * 8 + cb2) * 4096;
      p0 = *(const s8v*)&Wr[base + wn * 32 + wq * 8];
      p1 = *(const s8v*)&Wr[base + (wn + 64) * 32 + wq * 8];
    }

    // fragments
    const unsigned short* lBc = lB + (r & 1) * 4160;
    s8v bfr[8];
#pragma unroll
    for (int nt = 0; nt < 8; ++nt)
      bfr[nt] = *(const s8v*)&lBc[(quad * 130 + nt * 16 + lane15) * 8];
    s8v afr[4];
#pragma unroll
    for (int mt = 0; mt < 4; ++mt)
      afr[mt] = *(const s8v*)&lA[(quad * 794 + (oh_l + kh) * 132 + owb + mt * 16 + lane15 + kw) * 8];

#pragma unroll
    for (int mt = 0; mt < 4; ++mt)
#pragma unroll
      for (int nt = 0; nt < 8; ++nt)
        acc[mt][nt] = __builtin_amdgcn_mfma_f32_16x16x32_bf16(afr[mt], bfr[nt], acc[mt][nt], 0, 0, 0);
  }

  __syncthreads();  // all LDS reads done; lA region now reusable as ep
#pragma unroll 1
  for (int g = 0; g < 8; ++g) {  // cout groups of 16 (g == nt)
#pragma unroll
    for (int mt = 0; mt < 4; ++mt) {
      int m = oh_l * 128 + owb + mt * 16 + quad * 4;  // D: n=lane15, m(within 16)=quad*4+reg
      *(f4v*)&ep[lane15 * 260 + m] = acc[mt][g];
    }
    __syncthreads();
#pragma unroll
    for (int it = 0; it < 4; ++it) {
      int idx = it * 256 + tid;     // 0..1023
      int nl = idx >> 6;            // 0..15 (= it*4 + wave)
      int mi = (idx & 63) * 4;      // 0..252
      f4v v = *(const f4v*)&ep[nl * 260 + mi];
      int cout = g * 16 + nl;
      int ohh = oh0 + (mi >> 7);
      int oww = mi & 127;
      *(f4v*)&out[((size_t)(b * 128 + cout) * 128 + ohh) * 128 + oww] = v;
      float s = v.x + v.y + v.z + v.w;
      float ss = v.x * v.x + v.y * v.y + v.z * v.z + v.w * v.w;
#pragma unroll
      for (int off = 32; off > 0; off >>= 1) {  // full-wave: all 64 lanes share cout
        s += __shfl_xor(s, off);
        ss += __shfl_xor(ss, off);
      }
      if (lane == 0) { lsum[cout] = s; lssq[cout] = ss; }  // unique writer per cout
    }
    __syncthreads();
  }
  if (tid < 128) {
    int bin = (blockIdx.x & 31) * 256;
    atomicAdd(&pstats[bin + tid], lsum[tid]);
    atomicAdd(&pstats[bin + 128 + tid], lssq[tid]);
  }
}

// ---------------- BN: reduce 32 bins + scale/bias ----------------
__global__ void scalebias_kernel(const float* __restrict__ pstats, const float* __restrict__ gamma,
                                 const float* __restrict__ beta, float* __restrict__ sb) {
  __shared__ float red[256];
  int t = threadIdx.x;
  float s = 0.f;
#pragma unroll
  for (int bin = 0; bin < 32; ++bin) s += pstats[bin * 256 + t];
  red[t] = s;
  __syncthreads();
  if (t < 128) {
    float mean = red[t] * (1.f / 131072.f);
    float var = red[128 + t] * (1.f / 131072.f) - mean * mean;
    float inv = gamma[t] * rsqrtf(var + 1e-5f);
    sb[t] = inv;
    sb[128 + t] = beta[t] - mean * inv;
  }
}

// ---------------- Normalize + ReLU in-place on d_out ----------------
__global__ void norm_kernel(float* __restrict__ out, const float* __restrict__ sb) {
  int i = blockIdx.x * 256 + threadIdx.x;  // float4 index
  f4v v = ((f4v*)out)[i];
  int c = (i >> 12) & 127;
  float sc = sb[c], bi = sb[128 + c];
  v.x = fmaxf(fmaf(v.x, sc, bi), 0.f);
  v.y = fmaxf(fmaf(v.y, sc, bi), 0.f);
  v.z = fmaxf(fmaf(v.z, sc, bi), 0.f);
  v.w = fmaxf(fmaf(v.w, sc, bi), 0.f);
  ((f4v*)out)[i] = v;
}

extern "C" void kernel_launch(void* const* d_in, const int* in_sizes, int n_in,
                              void* d_out, int out_size, void* d_ws, size_t ws_size,
                              hipStream_t stream) {
  (void)in_sizes; (void)n_in; (void)out_size; (void)ws_size;
  const float* x = (const float*)d_in[0];
  const float* W = (const float*)d_in[1];
  const float* gamma = (const float*)d_in[2];
  const float* beta = (const float*)d_in[3];
  float* out = (float*)d_out;
  char* ws = (char*)d_ws;
  __hip_bfloat16* up = (__hip_bfloat16*)ws;                       // 67,108,864 B
  __hip_bfloat16* Wr = (__hip_bfloat16*)(ws + 67108864);          // 1,638,400 B
  float* pstats = (float*)(ws + 67108864 + 1638400);              // 32 bins x 256 floats
  float* sb = pstats + 32 * 256;

  hipMemsetAsync(pstats, 0, 32 * 256 * sizeof(float), stream);
  wpack_kernel<<<3200, 256, 0, stream>>>(W, Wr);
  upsample_kernel<<<512, 256, 0, stream>>>(x, up);
  conv_kernel<<<512, 256, 0, stream>>>(up, Wr, out, pstats);
  scalebias_kernel<<<1, 256, 0, stream>>>(pstats, gamma, beta, sb);
  norm_kernel<<<16384, 256, 0, stream>>>(out, sb);
}

// Round 6
// 1808.700 us; speedup vs baseline: 1.1702x; 1.1542x over previous
//
#include <hip/hip_runtime.h>
#include <hip/hip_bf16.h>
#include <stdint.h>

typedef short s8v __attribute__((ext_vector_type(8)));
typedef float f4v __attribute__((ext_vector_type(4)));

// ---------------- W pack: [co][ci][kh][kw] fp32 -> [pos 25][cb 8][cout 128][c32] bf16 ----------------
__global__ void wpack_kernel(const float* __restrict__ W, __hip_bfloat16* __restrict__ Wr) {
  int i = blockIdx.x * 256 + threadIdx.x;  // < 819200
  int c32 = i & 31;
  int n = (i >> 5) & 127;
  int cb = (i >> 12) & 7;
  int pos = i >> 15;
  Wr[i] = __float2bfloat16(W[(n * 256 + cb * 32 + c32) * 25 + pos]);
}

// ---------------- Upsample: x NCHW fp32 -> up [b][h 128][cb 8][w 128][c32] bf16 ----------------
__global__ __launch_bounds__(256, 2) void upsample_kernel(const float* __restrict__ x,
                                                          __hip_bfloat16* __restrict__ up) {
  __shared__ __hip_bfloat16 lx[10 * 48 * 66];  // [ih 10][iw 48][c 64 + 2 pad]
  const int tid = threadIdx.x;
  const int bx = blockIdx.x;
  const int owb = bx & 1;
  const int ohb = (bx >> 1) & 7;
  const int cbb = (bx >> 4) & 3;
  const int b = bx >> 6;
  const int oh0 = ohb * 16, ow0 = owb * 64, c0 = cbb * 64;
  const int ih0 = (oh0 >> 1) - 1;
  const int iw_lo = (ow0 >> 1) - 1;
  const int aligned = (iw_lo < 0 ? 0 : iw_lo) & ~15;

#pragma unroll 1
  for (int i = tid; i < 64 * 10 * 12; i += 256) {
    int c = i / 120;
    int rem = i - c * 120;
    int r = rem / 12;
    int w4 = (rem - r * 12) * 4;
    int gr = ih0 + r;
    gr = gr < 0 ? 0 : (gr > 63 ? 63 : gr);
    const float4 v = *(const float4*)&x[(((b * 256 + c0 + c) * 64) + gr) * 64 + aligned + w4];
    int base = (r * 48 + w4) * 66 + c;
    lx[base]       = __float2bfloat16(v.x);
    lx[base + 66]  = __float2bfloat16(v.y);
    lx[base + 132] = __float2bfloat16(v.z);
    lx[base + 198] = __float2bfloat16(v.w);
  }
  __syncthreads();

  const int c_l = tid & 63;
  const int owq = tid >> 6;
  const int cb_hi = cbb * 2 + (c_l >> 5);
  const int c32 = c_l & 31;
#pragma unroll 1
  for (int it = 0; it < 256; ++it) {
    int oh_l = it >> 4;
    int ow_l = (it & 15) * 4 + owq;
    int oh = oh0 + oh_l, ow = ow0 + ow_l;
    int ihA = (oh >> 1) - ((oh & 1) ^ 1);
    float wh = (oh & 1) ? 0.75f : 0.25f;
    int iwA = (ow >> 1) - ((ow & 1) ^ 1);
    float wwt = (ow & 1) ? 0.75f : 0.25f;
    int r0 = ihA - ih0;
    int w0 = (iwA < 0 ? 0 : iwA) - aligned;
    int w1t = iwA + 1; w1t = w1t > 63 ? 63 : w1t;
    int w1 = w1t - aligned;
    float t00 = __bfloat162float(lx[(r0 * 48 + w0) * 66 + c_l]);
    float t01 = __bfloat162float(lx[(r0 * 48 + w1) * 66 + c_l]);
    float t10 = __bfloat162float(lx[((r0 + 1) * 48 + w0) * 66 + c_l]);
    float t11 = __bfloat162float(lx[((r0 + 1) * 48 + w1) * 66 + c_l]);
    float v = wh * (wwt * t00 + (1.f - wwt) * t01) + (1.f - wh) * (wwt * t10 + (1.f - wwt) * t11);
    up[((((size_t)(b * 128 + oh) * 8) + cb_hi) * 128 + ow) * 32 + c32] = __float2bfloat16(v);
  }
}

// ---------------- Conv v5b: block = 1 oh row x 128 cout; weights global->reg (no in-loop barrier) ----
// grid: 1024 = b(8) x oh(128); 256 threads, waves 2x2: wm = ow half, wn = cout half; acc[4][4] = 64 regs.
// Round r = cb*25 + pos. lA (5 rows x 132 x 32ch) staged once per cb (8 barrier pairs total).
__global__ __launch_bounds__(256, 2) void conv_kernel(const __hip_bfloat16* __restrict__ up,
                                                      const __hip_bfloat16* __restrict__ Wr,
                                                      float* __restrict__ out,
                                                      float* __restrict__ pstats) {
  // lA chunk16 index = q*670 + row*134 + hw   (hw 0..131 halo coords; 2 pad chunks/row)
  // size = 4*670*16 = 42880 B.  ep [16][260] f32 (16640 B) aliases lA.  lsum/lssq at +42880.
  __shared__ __align__(16) char smem[42880 + 1024];
  unsigned short* lA = (unsigned short*)smem;
  float* ep = (float*)smem;
  float* lsum = (float*)(smem + 42880);
  float* lssq = lsum + 128;

  const int tid = threadIdx.x;
  const int lane = tid & 63;
  const int wave = tid >> 6;
  const int b = blockIdx.x >> 7;
  const int oh = blockIdx.x & 127;
  const int lane15 = lane & 15;
  const int quad = lane >> 4;
  const int wm = wave >> 1;           // ow half
  const int wn = wave & 1;            // cout half
  const s8v zero8 = {0, 0, 0, 0, 0, 0, 0, 0};

  lsum[tid] = 0.f;                    // lsum+lssq contiguous (256 floats)
  if (tid < 80) {                     // zero halo cols hw in {0,1,130,131}, all q,row
    int q = tid & 3;
    int rest = tid >> 2;              // 0..19
    int row = rest % 5;
    int h = rest / 5;                 // 0..3
    int hw = (h < 2) ? h : (128 + h); // 0,1,130,131  (FIXED: was 126+h, left 130/131 as LDS garbage)
    *(s8v*)&lA[(q * 670 + row * 134 + hw) * 8] = zero8;
  }

  f4v acc[4][4];
#pragma unroll
  for (int i = 0; i < 4; ++i)
#pragma unroll
    for (int j = 0; j < 4; ++j) acc[i][j] = (f4v){0.f, 0.f, 0.f, 0.f};

  // weight fragment global addresses: elem = (pos*8+cb)*4096 + wn*2048 + nt*512 + lane15*32 + quad*8
  const int wbase = wn * 2048 + lane15 * 32 + quad * 8;
  s8v bc[4], bn[4];
#pragma unroll
  for (int nt = 0; nt < 4; ++nt) bc[nt] = *(const s8v*)&Wr[wbase + nt * 512];  // round 0: pos0,cb0

#pragma unroll 1
  for (int r = 0; r < 200; ++r) {
    const int cb = r / 25;
    const int pos = r - cb * 25;
    const int kh = pos / 5;
    const int kw = pos - kh * 5;

    if (pos == 0) {  // stage lA: 5 input rows (oh-2..oh+2) x 128 chunks x 4 q = 2560 chunks
      __syncthreads();  // prior cb's lA reads complete (no-op at r=0)
      const size_t ubase = (((size_t)(b * 128) * 8) + cb) * 4096;
      s8v ra[10];
#pragma unroll
      for (int it = 0; it < 10; ++it) {
        int g = it * 256 + tid;       // 0..2559
        int row = g >> 9;             // 0..4 (wave-uniform per it)
        int ihg = oh - 2 + row;
        if (ihg >= 0 && ihg < 128)
          ra[it] = *(const s8v*)&up[ubase + (size_t)ihg * 32768 + (g & 511) * 8];
        else
          ra[it] = zero8;
      }
#pragma unroll
      for (int it = 0; it < 10; ++it) {
        int g = it * 256 + tid;
        int row = g >> 9;
        int iw = (g >> 2) & 127;
        int q = g & 3;
        *(s8v*)&lA[(q * 670 + row * 134 + iw + 2) * 8] = ra[it];
      }
      __syncthreads();  // staged lA visible
    }

    // prefetch next round's weight fragments (stay in flight across this round's MFMAs)
    {
      int rr = (r + 1 < 200) ? (r + 1) : 0;
      int cb2 = rr / 25;
      int pos2 = rr - cb2 * 25;
      const __hip_bfloat16* wp = Wr + (size_t)(pos2 * 8 + cb2) * 4096 + wbase;
#pragma unroll
      for (int nt = 0; nt < 4; ++nt) bn[nt] = *(const s8v*)&wp[nt * 512];
    }

    // A fragments from LDS (2-way bank aliasing only)
    s8v afr[4];
#pragma unroll
    for (int mt = 0; mt < 4; ++mt)
      afr[mt] = *(const s8v*)&lA[(quad * 670 + kh * 134 + wm * 64 + mt * 16 + lane15 + kw) * 8];

#pragma unroll
    for (int mt = 0; mt < 4; ++mt)
#pragma unroll
      for (int nt = 0; nt < 4; ++nt)
        acc[mt][nt] = __builtin_amdgcn_mfma_f32_16x16x32_bf16(afr[mt], bc[nt], acc[mt][nt], 0, 0, 0);

#pragma unroll
    for (int nt = 0; nt < 4; ++nt) bc[nt] = bn[nt];
  }

  __syncthreads();  // all lA reads done; reuse as ep
#pragma unroll 1
  for (int g = 0; g < 8; ++g) {  // cout group of 16: owner waves have wn == g>>2, nt = g&3
    if (wn == (g >> 2)) {
      const int nt = g & 3;
#pragma unroll
      for (int mt = 0; mt < 4; ++mt) {
        int m = wm * 64 + mt * 16 + quad * 4;  // D: n=lane15, m(within16)=quad*4+reg
        *(f4v*)&ep[lane15 * 260 + m] = acc[mt][nt];
      }
    }
    __syncthreads();
#pragma unroll
    for (int it = 0; it < 2; ++it) {
      int idx = it * 256 + tid;     // 0..511
      int nl = idx >> 5;            // 0..15
      int mi = (idx & 31) * 4;      // 0..124
      f4v v = *(const f4v*)&ep[nl * 260 + mi];
      int cout = g * 16 + nl;
      *(f4v*)&out[((size_t)(b * 128 + cout) * 128 + oh) * 128 + mi] = v;
      float s = v.x + v.y + v.z + v.w;
      float ss = v.x * v.x + v.y * v.y + v.z * v.z + v.w * v.w;
#pragma unroll
      for (int off = 16; off > 0; off >>= 1) {
        s += __shfl_xor(s, off, 32);
        ss += __shfl_xor(ss, off, 32);
      }
      if ((lane & 31) == 0) { lsum[cout] = s; lssq[cout] = ss; }  // unique writer
    }
    __syncthreads();
  }
  if (tid < 128) {
    int bin = (blockIdx.x & 31) * 256;
    atomicAdd(&pstats[bin + tid], lsum[tid]);
    atomicAdd(&pstats[bin + 128 + tid], lssq[tid]);
  }
}

// ---------------- BN: reduce 32 bins + scale/bias ----------------
__global__ void scalebias_kernel(const float* __restrict__ pstats, const float* __restrict__ gamma,
                                 const float* __restrict__ beta, float* __restrict__ sb) {
  __shared__ float red[256];
  int t = threadIdx.x;
  float s = 0.f;
#pragma unroll
  for (int bin = 0; bin < 32; ++bin) s += pstats[bin * 256 + t];
  red[t] = s;
  __syncthreads();
  if (t < 128) {
    float mean = red[t] * (1.f / 131072.f);
    float var = red[128 + t] * (1.f / 131072.f) - mean * mean;
    float inv = gamma[t] * rsqrtf(var + 1e-5f);
    sb[t] = inv;
    sb[128 + t] = beta[t] - mean * inv;
  }
}

// ---------------- Normalize + ReLU in-place on d_out ----------------
__global__ void norm_kernel(float* __restrict__ out, const float* __restrict__ sb) {
  int i = blockIdx.x * 256 + threadIdx.x;  // float4 index
  f4v v = ((f4v*)out)[i];
  int c = (i >> 12) & 127;
  float sc = sb[c], bi = sb[128 + c];
  v.x = fmaxf(fmaf(v.x, sc, bi), 0.f);
  v.y = fmaxf(fmaf(v.y, sc, bi), 0.f);
  v.z = fmaxf(fmaf(v.z, sc, bi), 0.f);
  v.w = fmaxf(fmaf(v.w, sc, bi), 0.f);
  ((f4v*)out)[i] = v;
}

extern "C" void kernel_launch(void* const* d_in, const int* in_sizes, int n_in,
                              void* d_out, int out_size, void* d_ws, size_t ws_size,
                              hipStream_t stream) {
  (void)in_sizes; (void)n_in; (void)out_size; (void)ws_size;
  const float* x = (const float*)d_in[0];
  const float* W = (const float*)d_in[1];
  const float* gamma = (const float*)d_in[2];
  const float* beta = (const float*)d_in[3];
  float* out = (float*)d_out;
  char* ws = (char*)d_ws;
  __hip_bfloat16* up = (__hip_bfloat16*)ws;                       // 67,108,864 B
  __hip_bfloat16* Wr = (__hip_bfloat16*)(ws + 67108864);          // 1,638,400 B
  float* pstats = (float*)(ws + 67108864 + 1638400);              // 32 bins x 256 floats
  float* sb = pstats + 32 * 256;

  hipMemsetAsync(pstats, 0, 32 * 256 * sizeof(float), stream);
  wpack_kernel<<<3200, 256, 0, stream>>>(W, Wr);
  upsample_kernel<<<512, 256, 0, stream>>>(x, up);
  conv_kernel<<<1024, 256, 0, stream>>>(up, Wr, out, pstats);
  scalebias_kernel<<<1, 256, 0, stream>>>(pstats, gamma, beta, sb);
  norm_kernel<<<16384, 256, 0, stream>>>(out, sb);
}